// Round 1
// baseline (206.674 us; speedup 1.0000x reference)
//
#include <hip/hip_runtime.h>
#include <math.h>

namespace {
constexpr int Bn = 8, Cn = 3, Hn = 512, Wn = 960;
constexpr int TPB = 256;
constexpr int CH4 = Wn / 4;                     // 240 float4 chunks per row
constexpr int NBLK1 = Bn * Hn * CH4 / TPB;      // 3840 (pass_warp blocks)
constexpr int NBLK2 = Bn * Hn * CH4 / TPB;      // 3840 (pass_ssim blocks, channel-looped)
constexpr size_t PLANE = (size_t)Bn * Hn * Wn;  // 3,932,160 px
// ws float layout: pad16 | red1 2*NBLK1 | red2 NBLK2 | bf16 planes (3*PLANE ushort) | vw plane (PLANE f32)
constexpr size_t RED1_OFF = 16;
constexpr size_t RED2_OFF = RED1_OFF + 2 * (size_t)NBLK1;   // 7696
constexpr size_t BF_OFF   = RED2_OFF + (size_t)NBLK2;       // 11536 floats (16B aligned)
constexpr size_t VW_OFF   = BF_OFF + (3 * PLANE) / 2;       // floats (16B aligned)
constexpr size_t WS_NEED  = (VW_OFF + PLANE) * sizeof(float);
constexpr float kC1 = 1e-4f;        // 0.01^2
constexpr float kC2 = 9e-4f;        // 0.03^2
constexpr float kEps2 = 1e-6f;      // 0.001^2
constexpr float A3 = 0.85f / 3.f;   // alpha/3
constexpr float B3 = 0.05f;         // (1-alpha)/3
}

__device__ __forceinline__ float gath1(const float* __restrict__ row, float xs) {
    float xf = floorf(xs);
    float wx = xs - xf;
    int xi = (int)xf;
    int a0 = min(max(xi, 0), Wn - 1);
    int a1 = min(max(xi + 1, 0), Wn - 1);
    return (1.f - wx) * row[a0] + wx * row[a1];
}

__device__ __forceinline__ unsigned short f2bf(float f) {   // RTNE
    unsigned u = __float_as_uint(f);
    u += 0x7fffu + ((u >> 16) & 1u);
    return (unsigned short)(u >> 16);
}
__device__ __forceinline__ float bf2f(unsigned short h) {
    return __uint_as_float(((unsigned)h) << 16);
}

// ---- Pass 1: warp right -> bf16 planes; vw plane (f32); per-block (v,l) slots ----
__global__ __launch_bounds__(TPB) void pass_warp(
    const float* __restrict__ right, const float* __restrict__ d_left,
    const float* __restrict__ d_right, const float* __restrict__ nonocc,
    unsigned short* __restrict__ wbf, float* __restrict__ vwp,
    float* __restrict__ red1)
{
    __shared__ float red[2][TPB / 64];
    const int t = threadIdx.x;
    int flat = blockIdx.x * TPB + t;
    int xq = flat % CH4;
    int rest = flat / CH4;
    int y = rest % Hn;
    int b = rest / Hn;
    int x0 = xq * 4;
    size_t rowoff = ((size_t)b * Hn + y) * Wn;

    float4 d4 = *(const float4*)(d_left + rowoff + x0);
    float4 n4 = *(const float4*)(nonocc + rowoff + x0);
    float ds[4] = {d4.x, d4.y, d4.z, d4.w};
    float ns[4] = {n4.x, n4.y, n4.z, n4.w};
    float xs[4], vw[4];
    float vsum = 0.f, lsum = 0.f;
    const float* drow = d_right + rowoff;
    #pragma unroll
    for (int j = 0; j < 4; ++j) {
        xs[j] = (float)(x0 + j) - ds[j];
        // gx in [-1,1]  <=>  xs in [0, W-1]
        float vm = (xs[j] >= 0.f && xs[j] <= (float)(Wn - 1)) ? 1.f : 0.f;
        vw[j] = vm * ns[j];
        vsum += vw[j];
        float drw = gath1(drow, xs[j]);
        float dd = ds[j] - drw;
        lsum += __builtin_amdgcn_sqrtf(dd * dd + kEps2) * vw[j];
    }
    *(float4*)(vwp + rowoff + x0) = float4{vw[0], vw[1], vw[2], vw[3]};

    #pragma unroll
    for (int c = 0; c < Cn; ++c) {
        const float* rrow = right + ((size_t)(b * Cn + c) * Hn + y) * Wn;
        ushort4 wv;
        wv.x = f2bf(gath1(rrow, xs[0]));
        wv.y = f2bf(gath1(rrow, xs[1]));
        wv.z = f2bf(gath1(rrow, xs[2]));
        wv.w = f2bf(gath1(rrow, xs[3]));
        *(ushort4*)(wbf + (size_t)c * PLANE + rowoff + x0) = wv;
    }

    #pragma unroll
    for (int off = 32; off > 0; off >>= 1) {
        vsum += __shfl_down(vsum, off);
        lsum += __shfl_down(lsum, off);
    }
    int lane = t & 63, wv = t >> 6;
    if (lane == 0) { red[0][wv] = vsum; red[1][wv] = lsum; }
    __syncthreads();
    if (t == 0) {
        float V = 0.f, L = 0.f;
        #pragma unroll
        for (int i = 0; i < TPB / 64; ++i) { V += red[0][i]; L += red[1][i]; }
        red1[2 * blockIdx.x + 0] = V;
        red1[2 * blockIdx.x + 1] = L;
    }
}

// ---- Pass 2: 3x3 SSIM + L1, all channels per thread; per-block p slot ----
__global__ __launch_bounds__(TPB) void pass_ssim(
    const float* __restrict__ left, const unsigned short* __restrict__ wbf,
    const float* __restrict__ vwp, float* __restrict__ red2)
{
    __shared__ float red[TPB / 64];
    const int t = threadIdx.x;
    int flat = blockIdx.x * TPB + t;
    int xq = flat % CH4;
    int rest = flat / CH4;
    int y = rest % Hn;
    int b = rest / Hn;
    int x0 = xq * 4;

    const float ml = (x0 > 0) ? 1.f : 0.f;
    const float mr = (x0 + 4 < Wn) ? 1.f : 0.f;
    const int xm1 = max(x0 - 1, 0);
    const int xp4 = min(x0 + 4, Wn - 1);
    const bool yint = (y > 0 && y < Hn - 1);

    float inv_cy = yint ? (1.f / 3.f) : 0.5f;
    float invj[4];
    #pragma unroll
    for (int j = 0; j < 4; ++j) {
        int xg = x0 + j;
        invj[j] = inv_cy * ((xg == 0 || xg == Wn - 1) ? 0.5f : (1.f / 3.f));
    }
    float4 v4 = *(const float4*)(vwp + ((size_t)b * Hn + y) * Wn + x0);
    float vws[4] = {v4.x, v4.y, v4.z, v4.w};

    float psum = 0.f;
    #pragma unroll
    for (int c = 0; c < Cn; ++c) {
        const float* lch = left + ((size_t)(b * Cn + c)) * Hn * Wn;
        const unsigned short* wch = wbf + (size_t)c * PLANE + (size_t)b * Hn * Wn;

        float l[3][6], w[3][6];
        if (yint) {                      // fast path: all 3 rows in-bounds
            #pragma unroll
            for (int r = 0; r < 3; ++r) {
                const float* lr_ = lch + (size_t)(y - 1 + r) * Wn;
                const unsigned short* wr_ = wch + (size_t)(y - 1 + r) * Wn;
                float4 lm = *(const float4*)(lr_ + x0);
                ushort4 wm = *(const ushort4*)(wr_ + x0);
                l[r][0] = lr_[xm1] * ml;
                l[r][1] = lm.x; l[r][2] = lm.y; l[r][3] = lm.z; l[r][4] = lm.w;
                l[r][5] = lr_[xp4] * mr;
                w[r][0] = bf2f(wr_[xm1]) * ml;
                w[r][1] = bf2f(wm.x); w[r][2] = bf2f(wm.y);
                w[r][3] = bf2f(wm.z); w[r][4] = bf2f(wm.w);
                w[r][5] = bf2f(wr_[xp4]) * mr;
            }
        } else {                          // border rows: mask + clamp
            #pragma unroll
            for (int r = 0; r < 3; ++r) {
                int yy = y - 1 + r;
                float ym = (yy >= 0 && yy < Hn) ? 1.f : 0.f;
                int ycl = min(max(yy, 0), Hn - 1);
                const float* lr_ = lch + (size_t)ycl * Wn;
                const unsigned short* wr_ = wch + (size_t)ycl * Wn;
                float4 lm = *(const float4*)(lr_ + x0);
                ushort4 wm = *(const ushort4*)(wr_ + x0);
                l[r][0] = lr_[xm1] * (ym * ml);
                l[r][1] = lm.x * ym; l[r][2] = lm.y * ym;
                l[r][3] = lm.z * ym; l[r][4] = lm.w * ym;
                l[r][5] = lr_[xp4] * (ym * mr);
                w[r][0] = bf2f(wr_[xm1]) * (ym * ml);
                w[r][1] = bf2f(wm.x) * ym; w[r][2] = bf2f(wm.y) * ym;
                w[r][3] = bf2f(wm.z) * ym; w[r][4] = bf2f(wm.w) * ym;
                w[r][5] = bf2f(wr_[xp4]) * (ym * mr);
            }
        }

        float cx[6], cy[6], cxx[6], cyy[6], cxy[6];
        #pragma unroll
        for (int q = 0; q < 6; ++q) {
            float l0 = l[0][q], l1 = l[1][q], l2 = l[2][q];
            float w0 = w[0][q], w1 = w[1][q], w2 = w[2][q];
            cx[q] = l0 + l1 + l2;
            cy[q] = w0 + w1 + w2;
            cxx[q] = fmaf(l0, l0, fmaf(l1, l1, l2 * l2));
            cyy[q] = fmaf(w0, w0, fmaf(w1, w1, w2 * w2));
            cxy[q] = fmaf(l0, w0, fmaf(l1, w1, l2 * w2));
        }

        #pragma unroll
        for (int j = 0; j < 4; ++j) {
            float Sx  = cx[j]  + cx[j + 1]  + cx[j + 2];
            float Sy  = cy[j]  + cy[j + 1]  + cy[j + 2];
            float Sxx = cxx[j] + cxx[j + 1] + cxx[j + 2];
            float Syy = cyy[j] + cyy[j + 1] + cyy[j + 2];
            float Sxy = cxy[j] + cxy[j + 1] + cxy[j + 2];
            float inv = invj[j];
            float mu_x = Sx * inv, mu_y = Sy * inv;
            float sig_x  = Sxx * inv - mu_x * mu_x;
            float sig_y  = Syy * inv - mu_y * mu_y;
            float sig_xy = Sxy * inv - mu_x * mu_y;
            float num = (2.f * mu_x * mu_y + kC1) * (2.f * sig_xy + kC2);
            float den = (mu_x * mu_x + mu_y * mu_y + kC1) * (sig_x + sig_y + kC2);
            float ssim = num * __builtin_amdgcn_rcpf(den + 1e-12f);
            float sm = fminf(fmaxf(0.5f * (1.f - ssim), 0.f), 1.f);
            float df = l[1][j + 1] - w[1][j + 1];
            float l1v = __builtin_amdgcn_sqrtf(df * df + kEps2);
            psum = fmaf(fmaf(A3, sm, B3 * l1v), vws[j], psum);
        }
    }

    #pragma unroll
    for (int off = 32; off > 0; off >>= 1) psum += __shfl_down(psum, off);
    int lane = t & 63, wv = t >> 6;
    if (lane == 0) red[wv] = psum;
    __syncthreads();
    if (t == 0) {
        float P = 0.f;
        #pragma unroll
        for (int i = 0; i < TPB / 64; ++i) P += red[i];
        red2[blockIdx.x] = P;
    }
}

// ---- Pass 3: single-block reduction over slots + finalize ----
__global__ __launch_bounds__(1024) void pass_reduce(
    const float* __restrict__ red1, const float* __restrict__ red2,
    float* __restrict__ out)
{
    __shared__ float sm[3][16];
    const int t = threadIdx.x;
    float V = 0.f, L = 0.f, P = 0.f;
    for (int i = t; i < NBLK1; i += 1024) {
        V += red1[2 * i + 0];
        L += red1[2 * i + 1];
    }
    for (int i = t; i < NBLK2; i += 1024) P += red2[i];
    #pragma unroll
    for (int off = 32; off > 0; off >>= 1) {
        V += __shfl_down(V, off);
        L += __shfl_down(L, off);
        P += __shfl_down(P, off);
    }
    int lane = t & 63, wv = t >> 6;
    if (lane == 0) { sm[0][wv] = V; sm[1][wv] = L; sm[2][wv] = P; }
    __syncthreads();
    if (t == 0) {
        float Va = 0.f, La = 0.f, Pa = 0.f;
        #pragma unroll
        for (int i = 0; i < 16; ++i) { Va += sm[0][i]; La += sm[1][i]; Pa += sm[2][i]; }
        float photo = Pa / (Va + 1e-6f);
        float lr = La / (Va + 1e-6f);
        out[0] = photo + 0.2f * lr;   // W_PHOTO=1, W_LR=0.2
        out[1] = photo;
        out[2] = lr;
        out[3] = Va * (1.f / (float)(Bn * Hn * Wn));
    }
}

// ---- Fallback (fused, only if ws too small) --------------------------------
namespace fb {
constexpr int RS = 8, SR = RS + 2, CW = 256, SC = CW + 2;
constexpr int NBX = (Wn + CW - 1) / CW, NSTRIP = Hn / RS;
constexpr int NBLK = NBX * NSTRIP * Bn;
}

__global__ __launch_bounds__(TPB) void stereo_fallback(
    const float* __restrict__ left, const float* __restrict__ right,
    const float* __restrict__ d_left, const float* __restrict__ d_right,
    const float* __restrict__ nonocc, float* __restrict__ acc,
    float* __restrict__ out)
{
    using namespace fb;
    __shared__ float sW[SR][SC];
    __shared__ float red[3][TPB / 64];
    const int t = threadIdx.x;
    const int bx = blockIdx.x, strip = blockIdx.y, b = blockIdx.z;
    const int y0 = strip * RS;
    const int x = bx * CW + t;
    const bool inb = (x < Wn);
    const int xc = min(x, Wn - 1);
    const float* leftB  = left   + (size_t)b * Cn * Hn * Wn;
    const float* rightB = right  + (size_t)b * Cn * Hn * Wn;
    const float* dL = d_left  + (size_t)b * Hn * Wn;
    const float* dR = d_right + (size_t)b * Hn * Wn;
    const float* no = nonocc  + (size_t)b * Hn * Wn;

    float vw_r[RS];
    float p_sum = 0.f, v_sum = 0.f, l_sum = 0.f;
    #pragma unroll
    for (int k = 0; k < RS; ++k) {
        int y = y0 + k;
        float d = dL[y * Wn + xc];
        float xs = (float)x - d;
        float vmask = (inb && xs >= 0.f && xs <= (float)(Wn - 1)) ? 1.f : 0.f;
        float vw = vmask * no[y * Wn + xc];
        vw_r[k] = vw; v_sum += vw;
        float drw = gath1(dR + (size_t)y * Wn, xs);
        float dd = d - drw;
        l_sum += sqrtf(dd * dd + kEps2) * vw;
    }
    const float xm_l = (x > 0) ? 1.f : 0.f;
    const float xm_r = (x < Wn - 1) ? 1.f : 0.f;
    const int xl = max(x - 1, 0), xr = min(x + 1, Wn - 1);
    const float inv_cx = (x == 0 || x == Wn - 1) ? 0.5f : (1.f / 3.f);
    const int g0 = bx * CW - 1;
    #pragma unroll
    for (int c = 0; c < Cn; ++c) {
        __syncthreads();
        const float* rchan = rightB + (size_t)c * Hn * Wn;
        #pragma unroll
        for (int r = 0; r < SR; ++r) {
            int y = y0 - 1 + r;
            bool yok = (y >= 0 && y < Hn);
            int g = g0 + t;
            float wv = 0.f;
            if (yok && g >= 0 && g < Wn)
                wv = gath1(rchan + (size_t)y * Wn, (float)g - dL[y * Wn + g]);
            sW[r][t] = wv;
            if (t < 2) {
                g = g0 + CW + t;
                wv = 0.f;
                if (yok && g >= 0 && g < Wn)
                    wv = gath1(rchan + (size_t)y * Wn, (float)g - dL[y * Wn + g]);
                sW[r][CW + t] = wv;
            }
        }
        __syncthreads();
        const float* lchan = leftB + (size_t)c * Hn * Wn;
        float lA[3][3], wA[3][3];
        #pragma unroll
        for (int r = 0; r < 2; ++r) {
            int y = y0 - 1 + r;
            int yy = min(max(y, 0), Hn - 1);
            float ym = (y >= 0 && y < Hn) ? 1.f : 0.f;
            const float* lrow = lchan + (size_t)yy * Wn;
            lA[r][0] = lrow[xl] * (ym * xm_l);
            lA[r][1] = lrow[xc] * ym;
            lA[r][2] = lrow[xr] * (ym * xm_r);
            wA[r][0] = sW[r][t]; wA[r][1] = sW[r][t + 1]; wA[r][2] = sW[r][t + 2];
        }
        #pragma unroll
        for (int k = 0; k < RS; ++k) {
            const int rn = k + 2, sn = rn % 3;
            int y = y0 - 1 + rn;
            int yy = min(max(y, 0), Hn - 1);
            float ym = (y >= 0 && y < Hn) ? 1.f : 0.f;
            const float* lrow = lchan + (size_t)yy * Wn;
            lA[sn][0] = lrow[xl] * (ym * xm_l);
            lA[sn][1] = lrow[xc] * ym;
            lA[sn][2] = lrow[xr] * (ym * xm_r);
            wA[sn][0] = sW[rn][t]; wA[sn][1] = sW[rn][t + 1]; wA[sn][2] = sW[rn][t + 2];
            float Sx = 0.f, Sy = 0.f, Sxx = 0.f, Syy = 0.f, Sxy = 0.f;
            #pragma unroll
            for (int s = 0; s < 3; ++s)
                #pragma unroll
                for (int j = 0; j < 3; ++j) {
                    float lv = lA[s][j], wv = wA[s][j];
                    Sx += lv; Sy += wv;
                    Sxx = fmaf(lv, lv, Sxx); Syy = fmaf(wv, wv, Syy); Sxy = fmaf(lv, wv, Sxy);
                }
            int yo = y0 + k;
            float inv = ((yo == 0 || yo == Hn - 1) ? 0.5f : (1.f / 3.f)) * inv_cx;
            float mu_x = Sx * inv, mu_y = Sy * inv;
            float sig_x = Sxx * inv - mu_x * mu_x;
            float sig_y = Syy * inv - mu_y * mu_y;
            float sig_xy = Sxy * inv - mu_x * mu_y;
            float num = (2.f * mu_x * mu_y + kC1) * (2.f * sig_xy + kC2);
            float den = (mu_x * mu_x + mu_y * mu_y + kC1) * (sig_x + sig_y + kC2);
            float ssim = num / (den + 1e-12f);
            float sm = fminf(fmaxf(0.5f * (1.f - ssim), 0.f), 1.f);
            int sc2 = (k + 1) % 3;
            float df = lA[sc2][1] - wA[sc2][1];
            p_sum += (A3 * sm + B3 * sqrtf(df * df + kEps2)) * vw_r[k];
        }
    }
    #pragma unroll
    for (int off = 32; off > 0; off >>= 1) {
        p_sum += __shfl_down(p_sum, off);
        v_sum += __shfl_down(v_sum, off);
        l_sum += __shfl_down(l_sum, off);
    }
    int lane = t & 63, wvi = t >> 6;
    if (lane == 0) { red[0][wvi] = p_sum; red[1][wvi] = v_sum; red[2][wvi] = l_sum; }
    __syncthreads();
    if (t == 0) {
        float P = 0.f, V = 0.f, L = 0.f;
        #pragma unroll
        for (int i = 0; i < TPB / 64; ++i) { P += red[0][i]; V += red[1][i]; L += red[2][i]; }
        atomicAdd(&acc[0], P);
        atomicAdd(&acc[1], V);
        atomicAdd(&acc[2], L);
        __threadfence();
        unsigned prev = atomicAdd((unsigned*)&acc[3], 1u);
        if (prev == fb::NBLK - 1) {
            float Pa = atomicAdd(&acc[0], 0.f);
            float Va = atomicAdd(&acc[1], 0.f);
            float La = atomicAdd(&acc[2], 0.f);
            float photo = Pa / (Va + 1e-6f);
            float lr = La / (Va + 1e-6f);
            out[0] = photo + 0.2f * lr;
            out[1] = photo;
            out[2] = lr;
            out[3] = Va * (1.f / (float)(Bn * Hn * Wn));
        }
    }
}

extern "C" void kernel_launch(void* const* d_in, const int* in_sizes, int n_in,
                              void* d_out, int out_size, void* d_ws, size_t ws_size,
                              hipStream_t stream) {
    const float* left   = (const float*)d_in[0];
    const float* right  = (const float*)d_in[1];
    const float* dl     = (const float*)d_in[2];
    const float* dr     = (const float*)d_in[3];
    const float* nonocc = (const float*)d_in[4];
    float* ws = (float*)d_ws;
    float* out = (float*)d_out;

    if (ws_size >= WS_NEED) {
        float* red1 = ws + RED1_OFF;
        float* red2 = ws + RED2_OFF;
        unsigned short* wbf = (unsigned short*)(ws + BF_OFF);
        float* vwp = ws + VW_OFF;
        pass_warp<<<NBLK1, TPB, 0, stream>>>(right, dl, dr, nonocc, wbf, vwp, red1);
        pass_ssim<<<NBLK2, TPB, 0, stream>>>(left, wbf, vwp, red2);
        pass_reduce<<<1, 1024, 0, stream>>>(red1, red2, out);
    } else {
        hipMemsetAsync(ws, 0, 4 * sizeof(float), stream);
        dim3 grid(fb::NBX, fb::NSTRIP, Bn);
        stereo_fallback<<<grid, TPB, 0, stream>>>(left, right, dl, dr, nonocc, ws, out);
    }
}

// Round 2
// 202.421 us; speedup vs baseline: 1.0210x; 1.0210x over previous
//
#include <hip/hip_runtime.h>
#include <math.h>

namespace {
constexpr int Bn = 8, Cn = 3, Hn = 512, Wn = 960;
constexpr int TPB = 256;
constexpr int CH4 = Wn / 4;                     // 240 float4 chunks per row
constexpr int NBLK1 = Bn * Hn;                  // 4096 (pass_warp: one row per block)
constexpr int NBLK2 = Bn * Hn * CH4 / TPB;      // 3840 (pass_ssim blocks, channel-looped)
constexpr size_t PLANE = (size_t)Bn * Hn * Wn;  // 3,932,160 px
// ws float layout: pad16 | red1 2*NBLK1 | red2 NBLK2 | bf16 planes (3*PLANE ushort) | vw plane (PLANE f32)
constexpr size_t RED1_OFF = 16;
constexpr size_t RED2_OFF = RED1_OFF + 2 * (size_t)NBLK1;   // 8208
constexpr size_t BF_OFF   = RED2_OFF + (size_t)NBLK2;       // 12048 floats (16B aligned)
constexpr size_t VW_OFF   = BF_OFF + (3 * PLANE) / 2;       // floats (16B aligned)
constexpr size_t WS_NEED  = (VW_OFF + PLANE) * sizeof(float);
constexpr float kC1 = 1e-4f;        // 0.01^2
constexpr float kC2 = 9e-4f;        // 0.03^2
constexpr float kEps2 = 1e-6f;      // 0.001^2
constexpr float A3 = 0.85f / 3.f;   // alpha/3
constexpr float B3 = 0.05f;         // (1-alpha)/3
}

__device__ __forceinline__ float gath1(const float* __restrict__ row, float xs) {
    float xf = floorf(xs);
    float wx = xs - xf;
    int xi = (int)xf;
    int a0 = min(max(xi, 0), Wn - 1);
    int a1 = min(max(xi + 1, 0), Wn - 1);
    return (1.f - wx) * row[a0] + wx * row[a1];
}

__device__ __forceinline__ unsigned short f2bf(float f) {   // RTNE
    unsigned u = __float_as_uint(f);
    u += 0x7fffu + ((u >> 16) & 1u);
    return (unsigned short)(u >> 16);
}
__device__ __forceinline__ float bf2f(unsigned short h) {
    return __uint_as_float(((unsigned)h) << 16);
}

// ---- Pass 1: warp right -> bf16 planes; vw plane (f32); per-block (v,l) slots ----
// One block per (b,y) row. Stage d_right row + 3 right-channel rows into LDS
// with coalesced float4 loads, then do all bilinear gathers from LDS.
// Arithmetic identical to the previous scattered-global version (bit-exact).
__global__ __launch_bounds__(TPB) void pass_warp(
    const float* __restrict__ right, const float* __restrict__ d_left,
    const float* __restrict__ d_right, const float* __restrict__ nonocc,
    unsigned short* __restrict__ wbf, float* __restrict__ vwp,
    float* __restrict__ red1)
{
    __shared__ float sD[Wn];          // d_right row   (3.75 KB)
    __shared__ float sR[3][Wn];       // right rows    (11.25 KB)
    __shared__ float red[2][TPB / 64];
    const int t = threadIdx.x;
    const int y = blockIdx.x & (Hn - 1);
    const int b = blockIdx.x >> 9;    // Hn = 512
    const size_t rowoff = ((size_t)b * Hn + y) * Wn;
    const size_t rbase  = ((size_t)b * Cn * Hn + (size_t)y) * Wn;  // right, ch 0, row y

    if (t < CH4) {   // 240 float4 loads per plane, fully coalesced
        ((float4*)sD)[t] = ((const float4*)(d_right + rowoff))[t];
        #pragma unroll
        for (int c = 0; c < Cn; ++c)
            ((float4*)sR[c])[t] = ((const float4*)(right + rbase + (size_t)c * Hn * Wn))[t];
    }
    __syncthreads();

    float vsum = 0.f, lsum = 0.f;
    if (t < CH4) {
        const int x0 = t * 4;
        float4 d4 = ((const float4*)(d_left + rowoff))[t];
        float4 n4 = ((const float4*)(nonocc + rowoff))[t];
        float ds[4] = {d4.x, d4.y, d4.z, d4.w};
        float ns[4] = {n4.x, n4.y, n4.z, n4.w};
        float xs[4], vw[4];
        int a0[4], a1[4];
        float wx[4];
        #pragma unroll
        for (int j = 0; j < 4; ++j) {
            xs[j] = (float)(x0 + j) - ds[j];
            float vm = (xs[j] >= 0.f && xs[j] <= (float)(Wn - 1)) ? 1.f : 0.f;
            vw[j] = vm * ns[j];
            vsum += vw[j];
            float xf = floorf(xs[j]);
            wx[j] = xs[j] - xf;
            int xi = (int)xf;
            a0[j] = min(max(xi, 0), Wn - 1);
            a1[j] = min(max(xi + 1, 0), Wn - 1);
            float drw = (1.f - wx[j]) * sD[a0[j]] + wx[j] * sD[a1[j]];
            float dd = ds[j] - drw;
            lsum += __builtin_amdgcn_sqrtf(dd * dd + kEps2) * vw[j];
        }
        ((float4*)(vwp + rowoff))[t] = float4{vw[0], vw[1], vw[2], vw[3]};

        #pragma unroll
        for (int c = 0; c < Cn; ++c) {
            ushort4 wv;
            wv.x = f2bf((1.f - wx[0]) * sR[c][a0[0]] + wx[0] * sR[c][a1[0]]);
            wv.y = f2bf((1.f - wx[1]) * sR[c][a0[1]] + wx[1] * sR[c][a1[1]]);
            wv.z = f2bf((1.f - wx[2]) * sR[c][a0[2]] + wx[2] * sR[c][a1[2]]);
            wv.w = f2bf((1.f - wx[3]) * sR[c][a0[3]] + wx[3] * sR[c][a1[3]]);
            ((ushort4*)(wbf + (size_t)c * PLANE + rowoff))[t] = wv;
        }
    }

    #pragma unroll
    for (int off = 32; off > 0; off >>= 1) {
        vsum += __shfl_down(vsum, off);
        lsum += __shfl_down(lsum, off);
    }
    int lane = t & 63, wv_ = t >> 6;
    if (lane == 0) { red[0][wv_] = vsum; red[1][wv_] = lsum; }
    __syncthreads();
    if (t == 0) {
        float V = 0.f, L = 0.f;
        #pragma unroll
        for (int i = 0; i < TPB / 64; ++i) { V += red[0][i]; L += red[1][i]; }
        red1[2 * blockIdx.x + 0] = V;
        red1[2 * blockIdx.x + 1] = L;
    }
}

// ---- Pass 2: 3x3 SSIM + L1, all channels per thread; per-block p slot ----
__global__ __launch_bounds__(TPB) void pass_ssim(
    const float* __restrict__ left, const unsigned short* __restrict__ wbf,
    const float* __restrict__ vwp, float* __restrict__ red2)
{
    __shared__ float red[TPB / 64];
    const int t = threadIdx.x;
    int flat = blockIdx.x * TPB + t;
    int xq = flat % CH4;
    int rest = flat / CH4;
    int y = rest % Hn;
    int b = rest / Hn;
    int x0 = xq * 4;

    const float ml = (x0 > 0) ? 1.f : 0.f;
    const float mr = (x0 + 4 < Wn) ? 1.f : 0.f;
    const int xm1 = max(x0 - 1, 0);
    const int xp4 = min(x0 + 4, Wn - 1);
    const bool yint = (y > 0 && y < Hn - 1);

    float inv_cy = yint ? (1.f / 3.f) : 0.5f;
    float invj[4];
    #pragma unroll
    for (int j = 0; j < 4; ++j) {
        int xg = x0 + j;
        invj[j] = inv_cy * ((xg == 0 || xg == Wn - 1) ? 0.5f : (1.f / 3.f));
    }
    float4 v4 = *(const float4*)(vwp + ((size_t)b * Hn + y) * Wn + x0);
    float vws[4] = {v4.x, v4.y, v4.z, v4.w};

    float psum = 0.f;
    #pragma unroll
    for (int c = 0; c < Cn; ++c) {
        const float* lch = left + ((size_t)(b * Cn + c)) * Hn * Wn;
        const unsigned short* wch = wbf + (size_t)c * PLANE + (size_t)b * Hn * Wn;

        float l[3][6], w[3][6];
        if (yint) {                      // fast path: all 3 rows in-bounds
            #pragma unroll
            for (int r = 0; r < 3; ++r) {
                const float* lr_ = lch + (size_t)(y - 1 + r) * Wn;
                const unsigned short* wr_ = wch + (size_t)(y - 1 + r) * Wn;
                float4 lm = *(const float4*)(lr_ + x0);
                ushort4 wm = *(const ushort4*)(wr_ + x0);
                l[r][0] = lr_[xm1] * ml;
                l[r][1] = lm.x; l[r][2] = lm.y; l[r][3] = lm.z; l[r][4] = lm.w;
                l[r][5] = lr_[xp4] * mr;
                w[r][0] = bf2f(wr_[xm1]) * ml;
                w[r][1] = bf2f(wm.x); w[r][2] = bf2f(wm.y);
                w[r][3] = bf2f(wm.z); w[r][4] = bf2f(wm.w);
                w[r][5] = bf2f(wr_[xp4]) * mr;
            }
        } else {                          // border rows: mask + clamp
            #pragma unroll
            for (int r = 0; r < 3; ++r) {
                int yy = y - 1 + r;
                float ym = (yy >= 0 && yy < Hn) ? 1.f : 0.f;
                int ycl = min(max(yy, 0), Hn - 1);
                const float* lr_ = lch + (size_t)ycl * Wn;
                const unsigned short* wr_ = wch + (size_t)ycl * Wn;
                float4 lm = *(const float4*)(lr_ + x0);
                ushort4 wm = *(const ushort4*)(wr_ + x0);
                l[r][0] = lr_[xm1] * (ym * ml);
                l[r][1] = lm.x * ym; l[r][2] = lm.y * ym;
                l[r][3] = lm.z * ym; l[r][4] = lm.w * ym;
                l[r][5] = lr_[xp4] * (ym * mr);
                w[r][0] = bf2f(wr_[xm1]) * (ym * ml);
                w[r][1] = bf2f(wm.x) * ym; w[r][2] = bf2f(wm.y) * ym;
                w[r][3] = bf2f(wm.z) * ym; w[r][4] = bf2f(wm.w) * ym;
                w[r][5] = bf2f(wr_[xp4]) * (ym * mr);
            }
        }

        float cx[6], cy[6], cxx[6], cyy[6], cxy[6];
        #pragma unroll
        for (int q = 0; q < 6; ++q) {
            float l0 = l[0][q], l1 = l[1][q], l2 = l[2][q];
            float w0 = w[0][q], w1 = w[1][q], w2 = w[2][q];
            cx[q] = l0 + l1 + l2;
            cy[q] = w0 + w1 + w2;
            cxx[q] = fmaf(l0, l0, fmaf(l1, l1, l2 * l2));
            cyy[q] = fmaf(w0, w0, fmaf(w1, w1, w2 * w2));
            cxy[q] = fmaf(l0, w0, fmaf(l1, w1, l2 * w2));
        }

        #pragma unroll
        for (int j = 0; j < 4; ++j) {
            float Sx  = cx[j]  + cx[j + 1]  + cx[j + 2];
            float Sy  = cy[j]  + cy[j + 1]  + cy[j + 2];
            float Sxx = cxx[j] + cxx[j + 1] + cxx[j + 2];
            float Syy = cyy[j] + cyy[j + 1] + cyy[j + 2];
            float Sxy = cxy[j] + cxy[j + 1] + cxy[j + 2];
            float inv = invj[j];
            float mu_x = Sx * inv, mu_y = Sy * inv;
            float sig_x  = Sxx * inv - mu_x * mu_x;
            float sig_y  = Syy * inv - mu_y * mu_y;
            float sig_xy = Sxy * inv - mu_x * mu_y;
            float num = (2.f * mu_x * mu_y + kC1) * (2.f * sig_xy + kC2);
            float den = (mu_x * mu_x + mu_y * mu_y + kC1) * (sig_x + sig_y + kC2);
            float ssim = num * __builtin_amdgcn_rcpf(den + 1e-12f);
            float sm = fminf(fmaxf(0.5f * (1.f - ssim), 0.f), 1.f);
            float df = l[1][j + 1] - w[1][j + 1];
            float l1v = __builtin_amdgcn_sqrtf(df * df + kEps2);
            psum = fmaf(fmaf(A3, sm, B3 * l1v), vws[j], psum);
        }
    }

    #pragma unroll
    for (int off = 32; off > 0; off >>= 1) psum += __shfl_down(psum, off);
    int lane = t & 63, wv = t >> 6;
    if (lane == 0) red[wv] = psum;
    __syncthreads();
    if (t == 0) {
        float P = 0.f;
        #pragma unroll
        for (int i = 0; i < TPB / 64; ++i) P += red[i];
        red2[blockIdx.x] = P;
    }
}

// ---- Pass 3: single-block reduction over slots + finalize ----
__global__ __launch_bounds__(1024) void pass_reduce(
    const float* __restrict__ red1, const float* __restrict__ red2,
    float* __restrict__ out)
{
    __shared__ float sm[3][16];
    const int t = threadIdx.x;
    float V = 0.f, L = 0.f, P = 0.f;
    for (int i = t; i < NBLK1; i += 1024) {
        V += red1[2 * i + 0];
        L += red1[2 * i + 1];
    }
    for (int i = t; i < NBLK2; i += 1024) P += red2[i];
    #pragma unroll
    for (int off = 32; off > 0; off >>= 1) {
        V += __shfl_down(V, off);
        L += __shfl_down(L, off);
        P += __shfl_down(P, off);
    }
    int lane = t & 63, wv = t >> 6;
    if (lane == 0) { sm[0][wv] = V; sm[1][wv] = L; sm[2][wv] = P; }
    __syncthreads();
    if (t == 0) {
        float Va = 0.f, La = 0.f, Pa = 0.f;
        #pragma unroll
        for (int i = 0; i < 16; ++i) { Va += sm[0][i]; La += sm[1][i]; Pa += sm[2][i]; }
        float photo = Pa / (Va + 1e-6f);
        float lr = La / (Va + 1e-6f);
        out[0] = photo + 0.2f * lr;   // W_PHOTO=1, W_LR=0.2
        out[1] = photo;
        out[2] = lr;
        out[3] = Va * (1.f / (float)(Bn * Hn * Wn));
    }
}

// ---- Fallback (fused, only if ws too small) --------------------------------
namespace fb {
constexpr int RS = 8, SR = RS + 2, CW = 256, SC = CW + 2;
constexpr int NBX = (Wn + CW - 1) / CW, NSTRIP = Hn / RS;
constexpr int NBLK = NBX * NSTRIP * Bn;
}

__global__ __launch_bounds__(TPB) void stereo_fallback(
    const float* __restrict__ left, const float* __restrict__ right,
    const float* __restrict__ d_left, const float* __restrict__ d_right,
    const float* __restrict__ nonocc, float* __restrict__ acc,
    float* __restrict__ out)
{
    using namespace fb;
    __shared__ float sW[SR][SC];
    __shared__ float red[3][TPB / 64];
    const int t = threadIdx.x;
    const int bx = blockIdx.x, strip = blockIdx.y, b = blockIdx.z;
    const int y0 = strip * RS;
    const int x = bx * CW + t;
    const bool inb = (x < Wn);
    const int xc = min(x, Wn - 1);
    const float* leftB  = left   + (size_t)b * Cn * Hn * Wn;
    const float* rightB = right  + (size_t)b * Cn * Hn * Wn;
    const float* dL = d_left  + (size_t)b * Hn * Wn;
    const float* dR = d_right + (size_t)b * Hn * Wn;
    const float* no = nonocc  + (size_t)b * Hn * Wn;

    float vw_r[RS];
    float p_sum = 0.f, v_sum = 0.f, l_sum = 0.f;
    #pragma unroll
    for (int k = 0; k < RS; ++k) {
        int y = y0 + k;
        float d = dL[y * Wn + xc];
        float xs = (float)x - d;
        float vmask = (inb && xs >= 0.f && xs <= (float)(Wn - 1)) ? 1.f : 0.f;
        float vw = vmask * no[y * Wn + xc];
        vw_r[k] = vw; v_sum += vw;
        float drw = gath1(dR + (size_t)y * Wn, xs);
        float dd = d - drw;
        l_sum += sqrtf(dd * dd + kEps2) * vw;
    }
    const float xm_l = (x > 0) ? 1.f : 0.f;
    const float xm_r = (x < Wn - 1) ? 1.f : 0.f;
    const int xl = max(x - 1, 0), xr = min(x + 1, Wn - 1);
    const float inv_cx = (x == 0 || x == Wn - 1) ? 0.5f : (1.f / 3.f);
    const int g0 = bx * CW - 1;
    #pragma unroll
    for (int c = 0; c < Cn; ++c) {
        __syncthreads();
        const float* rchan = rightB + (size_t)c * Hn * Wn;
        #pragma unroll
        for (int r = 0; r < SR; ++r) {
            int y = y0 - 1 + r;
            bool yok = (y >= 0 && y < Hn);
            int g = g0 + t;
            float wv = 0.f;
            if (yok && g >= 0 && g < Wn)
                wv = gath1(rchan + (size_t)y * Wn, (float)g - dL[y * Wn + g]);
            sW[r][t] = wv;
            if (t < 2) {
                g = g0 + CW + t;
                wv = 0.f;
                if (yok && g >= 0 && g < Wn)
                    wv = gath1(rchan + (size_t)y * Wn, (float)g - dL[y * Wn + g]);
                sW[r][CW + t] = wv;
            }
        }
        __syncthreads();
        const float* lchan = leftB + (size_t)c * Hn * Wn;
        float lA[3][3], wA[3][3];
        #pragma unroll
        for (int r = 0; r < 2; ++r) {
            int y = y0 - 1 + r;
            int yy = min(max(y, 0), Hn - 1);
            float ym = (y >= 0 && y < Hn) ? 1.f : 0.f;
            const float* lrow = lchan + (size_t)yy * Wn;
            lA[r][0] = lrow[xl] * (ym * xm_l);
            lA[r][1] = lrow[xc] * ym;
            lA[r][2] = lrow[xr] * (ym * xm_r);
            wA[r][0] = sW[r][t]; wA[r][1] = sW[r][t + 1]; wA[r][2] = sW[r][t + 2];
        }
        #pragma unroll
        for (int k = 0; k < RS; ++k) {
            const int rn = k + 2, sn = rn % 3;
            int y = y0 - 1 + rn;
            int yy = min(max(y, 0), Hn - 1);
            float ym = (y >= 0 && y < Hn) ? 1.f : 0.f;
            const float* lrow = lchan + (size_t)yy * Wn;
            lA[sn][0] = lrow[xl] * (ym * xm_l);
            lA[sn][1] = lrow[xc] * ym;
            lA[sn][2] = lrow[xr] * (ym * xm_r);
            wA[sn][0] = sW[rn][t]; wA[sn][1] = sW[rn][t + 1]; wA[sn][2] = sW[rn][t + 2];
            float Sx = 0.f, Sy = 0.f, Sxx = 0.f, Syy = 0.f, Sxy = 0.f;
            #pragma unroll
            for (int s = 0; s < 3; ++s)
                #pragma unroll
                for (int j = 0; j < 3; ++j) {
                    float lv = lA[s][j], wv = wA[s][j];
                    Sx += lv; Sy += wv;
                    Sxx = fmaf(lv, lv, Sxx); Syy = fmaf(wv, wv, Syy); Sxy = fmaf(lv, wv, Sxy);
                }
            int yo = y0 + k;
            float inv = ((yo == 0 || yo == Hn - 1) ? 0.5f : (1.f / 3.f)) * inv_cx;
            float mu_x = Sx * inv, mu_y = Sy * inv;
            float sig_x = Sxx * inv - mu_x * mu_x;
            float sig_y = Syy * inv - mu_y * mu_y;
            float sig_xy = Sxy * inv - mu_x * mu_y;
            float num = (2.f * mu_x * mu_y + kC1) * (2.f * sig_xy + kC2);
            float den = (mu_x * mu_x + mu_y * mu_y + kC1) * (sig_x + sig_y + kC2);
            float ssim = num / (den + 1e-12f);
            float sm = fminf(fmaxf(0.5f * (1.f - ssim), 0.f), 1.f);
            int sc2 = (k + 1) % 3;
            float df = lA[sc2][1] - wA[sc2][1];
            p_sum += (A3 * sm + B3 * sqrtf(df * df + kEps2)) * vw_r[k];
        }
    }
    #pragma unroll
    for (int off = 32; off > 0; off >>= 1) {
        p_sum += __shfl_down(p_sum, off);
        v_sum += __shfl_down(v_sum, off);
        l_sum += __shfl_down(l_sum, off);
    }
    int lane = t & 63, wvi = t >> 6;
    if (lane == 0) { red[0][wvi] = p_sum; red[1][wvi] = v_sum; red[2][wvi] = l_sum; }
    __syncthreads();
    if (t == 0) {
        float P = 0.f, V = 0.f, L = 0.f;
        #pragma unroll
        for (int i = 0; i < TPB / 64; ++i) { P += red[0][i]; V += red[1][i]; L += red[2][i]; }
        atomicAdd(&acc[0], P);
        atomicAdd(&acc[1], V);
        atomicAdd(&acc[2], L);
        __threadfence();
        unsigned prev = atomicAdd((unsigned*)&acc[3], 1u);
        if (prev == fb::NBLK - 1) {
            float Pa = atomicAdd(&acc[0], 0.f);
            float Va = atomicAdd(&acc[1], 0.f);
            float La = atomicAdd(&acc[2], 0.f);
            float photo = Pa / (Va + 1e-6f);
            float lr = La / (Va + 1e-6f);
            out[0] = photo + 0.2f * lr;
            out[1] = photo;
            out[2] = lr;
            out[3] = Va * (1.f / (float)(Bn * Hn * Wn));
        }
    }
}

extern "C" void kernel_launch(void* const* d_in, const int* in_sizes, int n_in,
                              void* d_out, int out_size, void* d_ws, size_t ws_size,
                              hipStream_t stream) {
    const float* left   = (const float*)d_in[0];
    const float* right  = (const float*)d_in[1];
    const float* dl     = (const float*)d_in[2];
    const float* dr     = (const float*)d_in[3];
    const float* nonocc = (const float*)d_in[4];
    float* ws = (float*)d_ws;
    float* out = (float*)d_out;

    if (ws_size >= WS_NEED) {
        float* red1 = ws + RED1_OFF;
        float* red2 = ws + RED2_OFF;
        unsigned short* wbf = (unsigned short*)(ws + BF_OFF);
        float* vwp = ws + VW_OFF;
        pass_warp<<<NBLK1, TPB, 0, stream>>>(right, dl, dr, nonocc, wbf, vwp, red1);
        pass_ssim<<<NBLK2, TPB, 0, stream>>>(left, wbf, vwp, red2);
        pass_reduce<<<1, 1024, 0, stream>>>(red1, red2, out);
    } else {
        hipMemsetAsync(ws, 0, 4 * sizeof(float), stream);
        dim3 grid(fb::NBX, fb::NSTRIP, Bn);
        stereo_fallback<<<grid, TPB, 0, stream>>>(left, right, dl, dr, nonocc, ws, out);
    }
}

// Round 9
// 183.354 us; speedup vs baseline: 1.1272x; 1.1040x over previous
//
#include <hip/hip_runtime.h>
#include <math.h>

namespace {
constexpr int Bn = 8, Cn = 3, Hn = 512, Wn = 960;
constexpr int TPB = 256;
constexpr int CH4 = Wn / 4;            // 240 float4 chunks per row
constexpr int RSF = 4, SRF = RSF + 2;  // fused: output rows per block, staged rows
constexpr int NSF = Hn / RSF;          // 128 strips
constexpr int NBLKF = Bn * NSF;        // 1024 fused blocks
constexpr size_t RED_OFF = 16;
constexpr size_t WS_NEED = (RED_OFF + 3 * (size_t)NBLKF) * sizeof(float);
constexpr float kC1 = 1e-4f;        // 0.01^2
constexpr float kC2 = 9e-4f;        // 0.03^2
constexpr float kEps2 = 1e-6f;      // 0.001^2
constexpr float A3 = 0.85f / 3.f;   // alpha/3
constexpr float B3 = 0.05f;         // (1-alpha)/3
}

__device__ __forceinline__ float gath1(const float* __restrict__ row, float xs) {
    float xf = floorf(xs);
    float wx = xs - xf;
    int xi = (int)xf;
    int a0 = min(max(xi, 0), Wn - 1);
    int a1 = min(max(xi + 1, 0), Wn - 1);
    return (1.f - wx) * row[a0] + wx * row[a1];
}

__device__ __forceinline__ unsigned short f2bf(float f) {   // RTNE
    unsigned u = __float_as_uint(f);
    u += 0x7fffu + ((u >> 16) & 1u);
    return (unsigned short)(u >> 16);
}
__device__ __forceinline__ float bf2f(unsigned short h) {
    return __uint_as_float(((unsigned)h) << 16);
}

// ---- Fused kernel: warp (into LDS bf16) + SSIM + L1 + lr, one barrier ----
// Block = (b, 4-row strip). Phase A warps right for 6 halo rows x 3 channels
// into LDS; phase B computes SSIM from LDS + rolling left rows from global.
// Arithmetic expressions bit-identical to the verified 3-pass version.
__global__ __launch_bounds__(TPB) void fused_main(
    const float* __restrict__ left, const float* __restrict__ right,
    const float* __restrict__ d_left, const float* __restrict__ d_right,
    const float* __restrict__ nonocc, float* __restrict__ red1)
{
    __shared__ unsigned short sW[Cn * SRF * Wn];   // 33.75 KB warped bf16
    __shared__ float red[3][TPB / 64];
    const int t = threadIdx.x;
    // XCD-chunked swizzle (bijective, 1024 % 8 == 0): each XCD owns one image
    const int nid = ((blockIdx.x & 7) << 7) | (blockIdx.x >> 3);
    const int b = nid >> 7;            // / NSF
    const int strip = nid & (NSF - 1);
    const int y0 = strip * RSF;
    const int x0 = t * 4;

    float vsum = 0.f, lsum = 0.f, psum = 0.f;
    float vw_reg[RSF][4];

    // ---------------- Phase A: warp halo rows into LDS ----------------
    if (t < CH4) {
        #pragma unroll
        for (int r = 0; r < SRF; ++r) {
            const int yy = y0 - 1 + r;
            if (yy < 0 || yy >= Hn) {          // OOB halo row -> zeros
                ushort4 z; z.x = z.y = z.z = z.w = 0;
                for (int c = 0; c < Cn; ++c)
                    *(ushort4*)&sW[(c * SRF + r) * Wn + x0] = z;
            } else {
                const size_t rowoff = ((size_t)b * Hn + yy) * Wn;
                float4 d4 = *(const float4*)(d_left + rowoff + x0);
                float ds[4] = {d4.x, d4.y, d4.z, d4.w};
                float xs[4], wx[4];
                int a0[4], a1[4];
                #pragma unroll
                for (int j = 0; j < 4; ++j) {
                    xs[j] = (float)(x0 + j) - ds[j];
                    float xf = floorf(xs[j]);
                    wx[j] = xs[j] - xf;
                    int xi = (int)xf;
                    a0[j] = min(max(xi, 0), Wn - 1);
                    a1[j] = min(max(xi + 1, 0), Wn - 1);
                }
                for (int c = 0; c < Cn; ++c) {
                    const float* rrow = right + ((size_t)(b * Cn + c) * Hn + yy) * Wn;
                    ushort4 wv;
                    wv.x = f2bf((1.f - wx[0]) * rrow[a0[0]] + wx[0] * rrow[a1[0]]);
                    wv.y = f2bf((1.f - wx[1]) * rrow[a0[1]] + wx[1] * rrow[a1[1]]);
                    wv.z = f2bf((1.f - wx[2]) * rrow[a0[2]] + wx[2] * rrow[a1[2]]);
                    wv.w = f2bf((1.f - wx[3]) * rrow[a0[3]] + wx[3] * rrow[a1[3]]);
                    *(ushort4*)&sW[(c * SRF + r) * Wn + x0] = wv;
                }
                if (r >= 1 && r <= RSF) {      // center row: vw + lr term
                    const int k = r - 1;
                    float4 n4 = *(const float4*)(nonocc + rowoff + x0);
                    float ns[4] = {n4.x, n4.y, n4.z, n4.w};
                    const float* drow = d_right + rowoff;
                    #pragma unroll
                    for (int j = 0; j < 4; ++j) {
                        float vm = (xs[j] >= 0.f && xs[j] <= (float)(Wn - 1)) ? 1.f : 0.f;
                        float vw = vm * ns[j];
                        vw_reg[k][j] = vw;
                        vsum += vw;
                        float drw = (1.f - wx[j]) * drow[a0[j]] + wx[j] * drow[a1[j]];
                        float dd = ds[j] - drw;
                        lsum += __builtin_amdgcn_sqrtf(dd * dd + kEps2) * vw;
                    }
                }
            }
        }
    }
    __syncthreads();

    // ---------------- Phase B: SSIM + L1 from LDS + global left ----------------
    if (t < CH4) {
        const float ml = (x0 > 0) ? 1.f : 0.f;
        const float mr = (x0 + 4 < Wn) ? 1.f : 0.f;
        const int xm1 = max(x0 - 1, 0);
        const int xp4 = min(x0 + 4, Wn - 1);
        float colf[4];
        #pragma unroll
        for (int j = 0; j < 4; ++j) {
            int xg = x0 + j;
            colf[j] = (xg == 0 || xg == Wn - 1) ? 0.5f : (1.f / 3.f);
        }
        float icy[RSF];
        #pragma unroll
        for (int k = 0; k < RSF; ++k) {
            int yo = y0 + k;
            icy[k] = (yo == 0 || yo == Hn - 1) ? 0.5f : (1.f / 3.f);
        }

#define LOADL(yy_, A) do {                                                   \
        int _y = (yy_);                                                      \
        if (_y < 0 || _y >= Hn) {                                            \
            A[0]=0.f; A[1]=0.f; A[2]=0.f; A[3]=0.f; A[4]=0.f; A[5]=0.f;      \
        } else {                                                             \
            const float* _r = lch + (size_t)_y * Wn;                         \
            float4 _m = *(const float4*)(_r + x0);                           \
            A[0] = _r[xm1] * ml;                                             \
            A[1] = _m.x; A[2] = _m.y; A[3] = _m.z; A[4] = _m.w;              \
            A[5] = _r[xp4] * mr;                                             \
        } } while (0)

#define LOADW(rr_, A) do {                                                   \
        const unsigned short* _w = wb + (rr_) * Wn;                          \
        ushort4 _m = *(const ushort4*)(_w + x0);                             \
        A[0] = bf2f(_w[xm1]) * ml;                                           \
        A[1] = bf2f(_m.x); A[2] = bf2f(_m.y);                                \
        A[3] = bf2f(_m.z); A[4] = bf2f(_m.w);                                \
        A[5] = bf2f(_w[xp4]) * mr;                                           \
        } while (0)

#define SSTEP(k_, T, M, Bt, WT, WM, WB) do {                                 \
        float cx[6], cy[6], cxx[6], cyy[6], cxy[6];                          \
        _Pragma("unroll")                                                    \
        for (int q = 0; q < 6; ++q) {                                        \
            float a0_ = T[q], a1_ = M[q], a2_ = Bt[q];                       \
            float b0_ = WT[q], b1_ = WM[q], b2_ = WB[q];                     \
            cx[q] = a0_ + a1_ + a2_;                                         \
            cy[q] = b0_ + b1_ + b2_;                                         \
            cxx[q] = fmaf(a0_, a0_, fmaf(a1_, a1_, a2_ * a2_));              \
            cyy[q] = fmaf(b0_, b0_, fmaf(b1_, b1_, b2_ * b2_));              \
            cxy[q] = fmaf(a0_, b0_, fmaf(a1_, b1_, a2_ * b2_));              \
        }                                                                    \
        _Pragma("unroll")                                                    \
        for (int j = 0; j < 4; ++j) {                                        \
            float Sx  = cx[j]  + cx[j + 1]  + cx[j + 2];                     \
            float Sy  = cy[j]  + cy[j + 1]  + cy[j + 2];                     \
            float Sxx = cxx[j] + cxx[j + 1] + cxx[j + 2];                    \
            float Syy = cyy[j] + cyy[j + 1] + cyy[j + 2];                    \
            float Sxy = cxy[j] + cxy[j + 1] + cxy[j + 2];                    \
            float inv = icy[k_] * colf[j];                                   \
            float mu_x = Sx * inv, mu_y = Sy * inv;                          \
            float sig_x  = Sxx * inv - mu_x * mu_x;                          \
            float sig_y  = Syy * inv - mu_y * mu_y;                          \
            float sig_xy = Sxy * inv - mu_x * mu_y;                          \
            float num = (2.f * mu_x * mu_y + kC1) * (2.f * sig_xy + kC2);    \
            float den = (mu_x * mu_x + mu_y * mu_y + kC1) * (sig_x + sig_y + kC2); \
            float ssim = num * __builtin_amdgcn_rcpf(den + 1e-12f);          \
            float sm_ = fminf(fmaxf(0.5f * (1.f - ssim), 0.f), 1.f);         \
            float df = M[j + 1] - WM[j + 1];                                 \
            float l1v = __builtin_amdgcn_sqrtf(df * df + kEps2);             \
            psum = fmaf(fmaf(A3, sm_, B3 * l1v), vw_reg[k_][j], psum);       \
        } } while (0)

        for (int c = 0; c < Cn; ++c) {
            const float* lch = left + (size_t)(b * Cn + c) * Hn * Wn;
            const unsigned short* wb = &sW[c * SRF * Wn];
            float l0[6], l1[6], l2[6], w0[6], w1[6], w2[6];
            LOADL(y0 - 1, l0); LOADW(0, w0);
            LOADL(y0,     l1); LOADW(1, w1);
            LOADL(y0 + 1, l2); LOADW(2, w2);
            SSTEP(0, l0, l1, l2, w0, w1, w2);
            LOADL(y0 + 2, l0); LOADW(3, w0);
            SSTEP(1, l1, l2, l0, w1, w2, w0);
            LOADL(y0 + 3, l1); LOADW(4, w1);
            SSTEP(2, l2, l0, l1, w2, w0, w1);
            LOADL(y0 + 4, l2); LOADW(5, w2);
            SSTEP(3, l0, l1, l2, w0, w1, w2);
        }
#undef LOADL
#undef LOADW
#undef SSTEP
    }

    // ---------------- block reduction ----------------
    #pragma unroll
    for (int off = 32; off > 0; off >>= 1) {
        vsum += __shfl_down(vsum, off);
        lsum += __shfl_down(lsum, off);
        psum += __shfl_down(psum, off);
    }
    int lane = t & 63, wv_ = t >> 6;
    if (lane == 0) { red[0][wv_] = vsum; red[1][wv_] = lsum; red[2][wv_] = psum; }
    __syncthreads();
    if (t == 0) {
        float V = 0.f, L = 0.f, P = 0.f;
        #pragma unroll
        for (int i = 0; i < TPB / 64; ++i) { V += red[0][i]; L += red[1][i]; P += red[2][i]; }
        red1[3 * blockIdx.x + 0] = V;
        red1[3 * blockIdx.x + 1] = L;
        red1[3 * blockIdx.x + 2] = P;
    }
}

// ---- Final reduction over 1024 block partials + finalize ----
__global__ __launch_bounds__(1024) void pass_reduce(
    const float* __restrict__ red1, float* __restrict__ out)
{
    __shared__ float sm[3][16];
    const int t = threadIdx.x;
    float V = 0.f, L = 0.f, P = 0.f;
    for (int i = t; i < NBLKF; i += 1024) {
        V += red1[3 * i + 0];
        L += red1[3 * i + 1];
        P += red1[3 * i + 2];
    }
    #pragma unroll
    for (int off = 32; off > 0; off >>= 1) {
        V += __shfl_down(V, off);
        L += __shfl_down(L, off);
        P += __shfl_down(P, off);
    }
    int lane = t & 63, wv = t >> 6;
    if (lane == 0) { sm[0][wv] = V; sm[1][wv] = L; sm[2][wv] = P; }
    __syncthreads();
    if (t == 0) {
        float Va = 0.f, La = 0.f, Pa = 0.f;
        #pragma unroll
        for (int i = 0; i < 16; ++i) { Va += sm[0][i]; La += sm[1][i]; Pa += sm[2][i]; }
        float photo = Pa / (Va + 1e-6f);
        float lr = La / (Va + 1e-6f);
        out[0] = photo + 0.2f * lr;   // W_PHOTO=1, W_LR=0.2
        out[1] = photo;
        out[2] = lr;
        out[3] = Va * (1.f / (float)(Bn * Hn * Wn));
    }
}

// ---- Fallback (fused strip kernel with atomics, only if ws too small) ------
namespace fb {
constexpr int RS = 8, SR = RS + 2, CW = 256, SC = CW + 2;
constexpr int NBX = (Wn + CW - 1) / CW, NSTRIP = Hn / RS;
constexpr int NBLK = NBX * NSTRIP * Bn;
}

__global__ __launch_bounds__(TPB) void stereo_fallback(
    const float* __restrict__ left, const float* __restrict__ right,
    const float* __restrict__ d_left, const float* __restrict__ d_right,
    const float* __restrict__ nonocc, float* __restrict__ acc,
    float* __restrict__ out)
{
    using namespace fb;
    __shared__ float sW[SR][SC];
    __shared__ float red[3][TPB / 64];
    const int t = threadIdx.x;
    const int bx = blockIdx.x, strip = blockIdx.y, b = blockIdx.z;
    const int y0 = strip * RS;
    const int x = bx * CW + t;
    const bool inb = (x < Wn);
    const int xc = min(x, Wn - 1);
    const float* leftB  = left   + (size_t)b * Cn * Hn * Wn;
    const float* rightB = right  + (size_t)b * Cn * Hn * Wn;
    const float* dL = d_left  + (size_t)b * Hn * Wn;
    const float* dR = d_right + (size_t)b * Hn * Wn;
    const float* no = nonocc  + (size_t)b * Hn * Wn;

    float vw_r[RS];
    float p_sum = 0.f, v_sum = 0.f, l_sum = 0.f;
    #pragma unroll
    for (int k = 0; k < RS; ++k) {
        int y = y0 + k;
        float d = dL[y * Wn + xc];
        float xs = (float)x - d;
        float vmask = (inb && xs >= 0.f && xs <= (float)(Wn - 1)) ? 1.f : 0.f;
        float vw = vmask * no[y * Wn + xc];
        vw_r[k] = vw; v_sum += vw;
        float drw = gath1(dR + (size_t)y * Wn, xs);
        float dd = d - drw;
        l_sum += sqrtf(dd * dd + kEps2) * vw;
    }
    const float xm_l = (x > 0) ? 1.f : 0.f;
    const float xm_r = (x < Wn - 1) ? 1.f : 0.f;
    const int xl = max(x - 1, 0), xr = min(x + 1, Wn - 1);
    const float inv_cx = (x == 0 || x == Wn - 1) ? 0.5f : (1.f / 3.f);
    const int g0 = bx * CW - 1;
    #pragma unroll
    for (int c = 0; c < Cn; ++c) {
        __syncthreads();
        const float* rchan = rightB + (size_t)c * Hn * Wn;
        #pragma unroll
        for (int r = 0; r < SR; ++r) {
            int y = y0 - 1 + r;
            bool yok = (y >= 0 && y < Hn);
            int g = g0 + t;
            float wv = 0.f;
            if (yok && g >= 0 && g < Wn)
                wv = gath1(rchan + (size_t)y * Wn, (float)g - dL[y * Wn + g]);
            sW[r][t] = wv;
            if (t < 2) {
                g = g0 + CW + t;
                wv = 0.f;
                if (yok && g >= 0 && g < Wn)
                    wv = gath1(rchan + (size_t)y * Wn, (float)g - dL[y * Wn + g]);
                sW[r][CW + t] = wv;
            }
        }
        __syncthreads();
        const float* lchan = leftB + (size_t)c * Hn * Wn;
        float lA[3][3], wA[3][3];
        #pragma unroll
        for (int r = 0; r < 2; ++r) {
            int y = y0 - 1 + r;
            int yy = min(max(y, 0), Hn - 1);
            float ym = (y >= 0 && y < Hn) ? 1.f : 0.f;
            const float* lrow = lchan + (size_t)yy * Wn;
            lA[r][0] = lrow[xl] * (ym * xm_l);
            lA[r][1] = lrow[xc] * ym;
            lA[r][2] = lrow[xr] * (ym * xm_r);
            wA[r][0] = sW[r][t]; wA[r][1] = sW[r][t + 1]; wA[r][2] = sW[r][t + 2];
        }
        #pragma unroll
        for (int k = 0; k < RS; ++k) {
            const int rn = k + 2, sn = rn % 3;
            int y = y0 - 1 + rn;
            int yy = min(max(y, 0), Hn - 1);
            float ym = (y >= 0 && y < Hn) ? 1.f : 0.f;
            const float* lrow = lchan + (size_t)yy * Wn;
            lA[sn][0] = lrow[xl] * (ym * xm_l);
            lA[sn][1] = lrow[xc] * ym;
            lA[sn][2] = lrow[xr] * (ym * xm_r);
            wA[sn][0] = sW[rn][t]; wA[sn][1] = sW[rn][t + 1]; wA[sn][2] = sW[rn][t + 2];
            float Sx = 0.f, Sy = 0.f, Sxx = 0.f, Syy = 0.f, Sxy = 0.f;
            #pragma unroll
            for (int s = 0; s < 3; ++s)
                #pragma unroll
                for (int j = 0; j < 3; ++j) {
                    float lv = lA[s][j], wv = wA[s][j];
                    Sx += lv; Sy += wv;
                    Sxx = fmaf(lv, lv, Sxx); Syy = fmaf(wv, wv, Syy); Sxy = fmaf(lv, wv, Sxy);
                }
            int yo = y0 + k;
            float inv = ((yo == 0 || yo == Hn - 1) ? 0.5f : (1.f / 3.f)) * inv_cx;
            float mu_x = Sx * inv, mu_y = Sy * inv;
            float sig_x = Sxx * inv - mu_x * mu_x;
            float sig_y = Syy * inv - mu_y * mu_y;
            float sig_xy = Sxy * inv - mu_x * mu_y;
            float num = (2.f * mu_x * mu_y + kC1) * (2.f * sig_xy + kC2);
            float den = (mu_x * mu_x + mu_y * mu_y + kC1) * (sig_x + sig_y + kC2);
            float ssim = num / (den + 1e-12f);
            float sm = fminf(fmaxf(0.5f * (1.f - ssim), 0.f), 1.f);
            int sc2 = (k + 1) % 3;
            float df = lA[sc2][1] - wA[sc2][1];
            p_sum += (A3 * sm + B3 * sqrtf(df * df + kEps2)) * vw_r[k];
        }
    }
    #pragma unroll
    for (int off = 32; off > 0; off >>= 1) {
        p_sum += __shfl_down(p_sum, off);
        v_sum += __shfl_down(v_sum, off);
        l_sum += __shfl_down(l_sum, off);
    }
    int lane = t & 63, wvi = t >> 6;
    if (lane == 0) { red[0][wvi] = p_sum; red[1][wvi] = v_sum; red[2][wvi] = l_sum; }
    __syncthreads();
    if (t == 0) {
        float P = 0.f, V = 0.f, L = 0.f;
        #pragma unroll
        for (int i = 0; i < TPB / 64; ++i) { P += red[0][i]; V += red[1][i]; L += red[2][i]; }
        atomicAdd(&acc[0], P);
        atomicAdd(&acc[1], V);
        atomicAdd(&acc[2], L);
        __threadfence();
        unsigned prev = atomicAdd((unsigned*)&acc[3], 1u);
        if (prev == fb::NBLK - 1) {
            float Pa = atomicAdd(&acc[0], 0.f);
            float Va = atomicAdd(&acc[1], 0.f);
            float La = atomicAdd(&acc[2], 0.f);
            float photo = Pa / (Va + 1e-6f);
            float lr = La / (Va + 1e-6f);
            out[0] = photo + 0.2f * lr;
            out[1] = photo;
            out[2] = lr;
            out[3] = Va * (1.f / (float)(Bn * Hn * Wn));
        }
    }
}

extern "C" void kernel_launch(void* const* d_in, const int* in_sizes, int n_in,
                              void* d_out, int out_size, void* d_ws, size_t ws_size,
                              hipStream_t stream) {
    const float* left   = (const float*)d_in[0];
    const float* right  = (const float*)d_in[1];
    const float* dl     = (const float*)d_in[2];
    const float* dr     = (const float*)d_in[3];
    const float* nonocc = (const float*)d_in[4];
    float* ws = (float*)d_ws;
    float* out = (float*)d_out;

    if (ws_size >= WS_NEED) {
        float* red1 = ws + RED_OFF;
        fused_main<<<NBLKF, TPB, 0, stream>>>(left, right, dl, dr, nonocc, red1);
        pass_reduce<<<1, 1024, 0, stream>>>(red1, out);
    } else {
        (void)hipMemsetAsync(ws, 0, 4 * sizeof(float), stream);
        dim3 grid(fb::NBX, fb::NSTRIP, Bn);
        stereo_fallback<<<grid, TPB, 0, stream>>>(left, right, dl, dr, nonocc, ws, out);
    }
}

// Round 12
// 174.413 us; speedup vs baseline: 1.1850x; 1.0513x over previous
//
#include <hip/hip_runtime.h>
#include <math.h>

namespace {
constexpr int Bn = 8, Cn = 3, Hn = 512, Wn = 960;
constexpr int TPB = 256;
constexpr int CH4 = Wn / 4;            // 240 float4 chunks per row
constexpr int RSF = 4, SRF = RSF + 2;  // fused: output rows per block, staged rows
constexpr int NSF = Hn / RSF;          // 128 strips
constexpr int NBLKF = Bn * NSF;        // 1024 fused blocks
constexpr size_t RED_OFF = 16;
constexpr size_t WS_NEED = (RED_OFF + 3 * (size_t)NBLKF) * sizeof(float);
constexpr float kC1 = 1e-4f;        // 0.01^2
constexpr float kC2 = 9e-4f;        // 0.03^2
constexpr float kEps2 = 1e-6f;      // 0.001^2
constexpr float A3 = 0.85f / 3.f;   // alpha/3
constexpr float B3 = 0.05f;         // (1-alpha)/3
}

// 4-byte-aligned float2 for merged two-tap gather (one 8B load, both taps)
typedef float f2u __attribute__((ext_vector_type(2), aligned(4)));

__device__ __forceinline__ float gath1(const float* __restrict__ row, float xs) {
    float xf = floorf(xs);
    float wx = xs - xf;
    int xi = (int)xf;
    int a0 = min(max(xi, 0), Wn - 1);
    int a1 = min(max(xi + 1, 0), Wn - 1);
    return (1.f - wx) * row[a0] + wx * row[a1];
}

__device__ __forceinline__ unsigned short f2bf(float f) {   // RTNE
    unsigned u = __float_as_uint(f);
    u += 0x7fffu + ((u >> 16) & 1u);
    return (unsigned short)(u >> 16);
}
__device__ __forceinline__ float bf2f(unsigned short h) {
    return __uint_as_float(((unsigned)h) << 16);
}

// ---- Fused kernel: warp (into LDS bf16) + SSIM + L1 + lr, one barrier ----
// Block = (b, 4-row strip). Phase A warps right for 6 halo rows x 3 channels
// into LDS (merged-tap 8B gathers); phase B computes SSIM from LDS + rolling
// left rows. Gather values bit-identical to the two-scalar-tap version:
//   v0 = row[clamp(xi,0,W-1)], v1 = row[clamp(xi+1,0,W-1)]
// via one float2 at clamp(xi,0,W-2) + edge selects (xi in [-64, W-1]).
__global__ __launch_bounds__(TPB) void fused_main(
    const float* __restrict__ left, const float* __restrict__ right,
    const float* __restrict__ d_left, const float* __restrict__ d_right,
    const float* __restrict__ nonocc, float* __restrict__ red1)
{
    __shared__ unsigned short sW[Cn * SRF * Wn];   // 33.75 KB warped bf16
    __shared__ float red[3][TPB / 64];
    const int t = threadIdx.x;
    // XCD-chunked swizzle (bijective, 1024 % 8 == 0): each XCD owns one image
    const int nid = ((blockIdx.x & 7) << 7) | (blockIdx.x >> 3);
    const int b = nid >> 7;            // / NSF
    const int strip = nid & (NSF - 1);
    const int y0 = strip * RSF;
    const int x0 = t * 4;

    float vsum = 0.f, lsum = 0.f, psum = 0.f;
    float vw_reg[RSF][4];

    // ---------------- Phase A: warp halo rows into LDS ----------------
    if (t < CH4) {
        #pragma unroll
        for (int r = 0; r < SRF; ++r) {
            const int yy = y0 - 1 + r;
            if (yy < 0 || yy >= Hn) {          // OOB halo row -> zeros
                ushort4 z; z.x = z.y = z.z = z.w = 0;
                for (int c = 0; c < Cn; ++c)
                    *(ushort4*)&sW[(c * SRF + r) * Wn + x0] = z;
            } else {
                const size_t rowoff = ((size_t)b * Hn + yy) * Wn;
                float4 d4 = *(const float4*)(d_left + rowoff + x0);
                float ds[4] = {d4.x, d4.y, d4.z, d4.w};
                float xs[4], wx[4];
                int ad[4];
                bool shi[4], slo[4];
                #pragma unroll
                for (int j = 0; j < 4; ++j) {
                    xs[j] = (float)(x0 + j) - ds[j];
                    float xf = floorf(xs[j]);
                    wx[j] = xs[j] - xf;
                    int xi = (int)xf;
                    ad[j] = min(max(xi, 0), Wn - 2);
                    shi[j] = (xi >= Wn - 1);
                    slo[j] = (xi < 0);
                }
                for (int c = 0; c < Cn; ++c) {
                    const float* rrow = right + ((size_t)(b * Cn + c) * Hn + yy) * Wn;
                    ushort4 wv;
                    #pragma unroll
                    for (int j = 0; j < 4; ++j) {
                        f2u g = *(const f2u*)(rrow + ad[j]);
                        float v0 = shi[j] ? g[1] : g[0];
                        float v1 = slo[j] ? g[0] : g[1];
                        unsigned short bv = f2bf((1.f - wx[j]) * v0 + wx[j] * v1);
                        if (j == 0) wv.x = bv;
                        else if (j == 1) wv.y = bv;
                        else if (j == 2) wv.z = bv;
                        else wv.w = bv;
                    }
                    *(ushort4*)&sW[(c * SRF + r) * Wn + x0] = wv;
                }
                if (r >= 1 && r <= RSF) {      // center row: vw + lr term
                    const int k = r - 1;
                    float4 n4 = *(const float4*)(nonocc + rowoff + x0);
                    float ns[4] = {n4.x, n4.y, n4.z, n4.w};
                    const float* drow = d_right + rowoff;
                    #pragma unroll
                    for (int j = 0; j < 4; ++j) {
                        float vm = (xs[j] >= 0.f && xs[j] <= (float)(Wn - 1)) ? 1.f : 0.f;
                        float vw = vm * ns[j];
                        vw_reg[k][j] = vw;
                        vsum += vw;
                        f2u g = *(const f2u*)(drow + ad[j]);
                        float v0 = shi[j] ? g[1] : g[0];
                        float v1 = slo[j] ? g[0] : g[1];
                        float drw = (1.f - wx[j]) * v0 + wx[j] * v1;
                        float dd = ds[j] - drw;
                        lsum += __builtin_amdgcn_sqrtf(dd * dd + kEps2) * vw;
                    }
                }
            }
        }
    }
    __syncthreads();

    // ---------------- Phase B: SSIM + L1 from LDS + global left ----------------
    if (t < CH4) {
        const float ml = (x0 > 0) ? 1.f : 0.f;
        const float mr = (x0 + 4 < Wn) ? 1.f : 0.f;
        const int xm1 = max(x0 - 1, 0);
        const int xp4 = min(x0 + 4, Wn - 1);
        float colf[4];
        #pragma unroll
        for (int j = 0; j < 4; ++j) {
            int xg = x0 + j;
            colf[j] = (xg == 0 || xg == Wn - 1) ? 0.5f : (1.f / 3.f);
        }
        float icy[RSF];
        #pragma unroll
        for (int k = 0; k < RSF; ++k) {
            int yo = y0 + k;
            icy[k] = (yo == 0 || yo == Hn - 1) ? 0.5f : (1.f / 3.f);
        }

#define LOADL(yy_, A) do {                                                   \
        int _y = (yy_);                                                      \
        if (_y < 0 || _y >= Hn) {                                            \
            A[0]=0.f; A[1]=0.f; A[2]=0.f; A[3]=0.f; A[4]=0.f; A[5]=0.f;      \
        } else {                                                             \
            const float* _r = lch + (size_t)_y * Wn;                         \
            float4 _m = *(const float4*)(_r + x0);                           \
            A[0] = _r[xm1] * ml;                                             \
            A[1] = _m.x; A[2] = _m.y; A[3] = _m.z; A[4] = _m.w;              \
            A[5] = _r[xp4] * mr;                                             \
        } } while (0)

#define LOADW(rr_, A) do {                                                   \
        const unsigned short* _w = wb + (rr_) * Wn;                          \
        ushort4 _m = *(const ushort4*)(_w + x0);                             \
        A[0] = bf2f(_w[xm1]) * ml;                                           \
        A[1] = bf2f(_m.x); A[2] = bf2f(_m.y);                                \
        A[3] = bf2f(_m.z); A[4] = bf2f(_m.w);                                \
        A[5] = bf2f(_w[xp4]) * mr;                                           \
        } while (0)

#define SSTEP(k_, T, M, Bt, WT, WM, WB) do {                                 \
        float cx[6], cy[6], cxx[6], cyy[6], cxy[6];                          \
        _Pragma("unroll")                                                    \
        for (int q = 0; q < 6; ++q) {                                        \
            float a0_ = T[q], a1_ = M[q], a2_ = Bt[q];                       \
            float b0_ = WT[q], b1_ = WM[q], b2_ = WB[q];                     \
            cx[q] = a0_ + a1_ + a2_;                                         \
            cy[q] = b0_ + b1_ + b2_;                                         \
            cxx[q] = fmaf(a0_, a0_, fmaf(a1_, a1_, a2_ * a2_));              \
            cyy[q] = fmaf(b0_, b0_, fmaf(b1_, b1_, b2_ * b2_));              \
            cxy[q] = fmaf(a0_, b0_, fmaf(a1_, b1_, a2_ * b2_));              \
        }                                                                    \
        _Pragma("unroll")                                                    \
        for (int j = 0; j < 4; ++j) {                                        \
            float Sx  = cx[j]  + cx[j + 1]  + cx[j + 2];                     \
            float Sy  = cy[j]  + cy[j + 1]  + cy[j + 2];                     \
            float Sxx = cxx[j] + cxx[j + 1] + cxx[j + 2];                    \
            float Syy = cyy[j] + cyy[j + 1] + cyy[j + 2];                    \
            float Sxy = cxy[j] + cxy[j + 1] + cxy[j + 2];                    \
            float inv = icy[k_] * colf[j];                                   \
            float mu_x = Sx * inv, mu_y = Sy * inv;                          \
            float sig_x  = Sxx * inv - mu_x * mu_x;                          \
            float sig_y  = Syy * inv - mu_y * mu_y;                          \
            float sig_xy = Sxy * inv - mu_x * mu_y;                          \
            float num = (2.f * mu_x * mu_y + kC1) * (2.f * sig_xy + kC2);    \
            float den = (mu_x * mu_x + mu_y * mu_y + kC1) * (sig_x + sig_y + kC2); \
            float ssim = num * __builtin_amdgcn_rcpf(den + 1e-12f);          \
            float sm_ = fminf(fmaxf(0.5f * (1.f - ssim), 0.f), 1.f);         \
            float df = M[j + 1] - WM[j + 1];                                 \
            float l1v = __builtin_amdgcn_sqrtf(df * df + kEps2);             \
            psum = fmaf(fmaf(A3, sm_, B3 * l1v), vw_reg[k_][j], psum);       \
        } } while (0)

        for (int c = 0; c < Cn; ++c) {
            const float* lch = left + (size_t)(b * Cn + c) * Hn * Wn;
            const unsigned short* wb = &sW[c * SRF * Wn];
            float l0[6], l1[6], l2[6], w0[6], w1[6], w2[6];
            LOADL(y0 - 1, l0); LOADW(0, w0);
            LOADL(y0,     l1); LOADW(1, w1);
            LOADL(y0 + 1, l2); LOADW(2, w2);
            SSTEP(0, l0, l1, l2, w0, w1, w2);
            LOADL(y0 + 2, l0); LOADW(3, w0);
            SSTEP(1, l1, l2, l0, w1, w2, w0);
            LOADL(y0 + 3, l1); LOADW(4, w1);
            SSTEP(2, l2, l0, l1, w2, w0, w1);
            LOADL(y0 + 4, l2); LOADW(5, w2);
            SSTEP(3, l0, l1, l2, w0, w1, w2);
        }
#undef LOADL
#undef LOADW
#undef SSTEP
    }

    // ---------------- block reduction ----------------
    #pragma unroll
    for (int off = 32; off > 0; off >>= 1) {
        vsum += __shfl_down(vsum, off);
        lsum += __shfl_down(lsum, off);
        psum += __shfl_down(psum, off);
    }
    int lane = t & 63, wv_ = t >> 6;
    if (lane == 0) { red[0][wv_] = vsum; red[1][wv_] = lsum; red[2][wv_] = psum; }
    __syncthreads();
    if (t == 0) {
        float V = 0.f, L = 0.f, P = 0.f;
        #pragma unroll
        for (int i = 0; i < TPB / 64; ++i) { V += red[0][i]; L += red[1][i]; P += red[2][i]; }
        red1[3 * blockIdx.x + 0] = V;
        red1[3 * blockIdx.x + 1] = L;
        red1[3 * blockIdx.x + 2] = P;
    }
}

// ---- Final reduction over 1024 block partials + finalize ----
__global__ __launch_bounds__(1024) void pass_reduce(
    const float* __restrict__ red1, float* __restrict__ out)
{
    __shared__ float sm[3][16];
    const int t = threadIdx.x;
    float V = 0.f, L = 0.f, P = 0.f;
    for (int i = t; i < NBLKF; i += 1024) {
        V += red1[3 * i + 0];
        L += red1[3 * i + 1];
        P += red1[3 * i + 2];
    }
    #pragma unroll
    for (int off = 32; off > 0; off >>= 1) {
        V += __shfl_down(V, off);
        L += __shfl_down(L, off);
        P += __shfl_down(P, off);
    }
    int lane = t & 63, wv = t >> 6;
    if (lane == 0) { sm[0][wv] = V; sm[1][wv] = L; sm[2][wv] = P; }
    __syncthreads();
    if (t == 0) {
        float Va = 0.f, La = 0.f, Pa = 0.f;
        #pragma unroll
        for (int i = 0; i < 16; ++i) { Va += sm[0][i]; La += sm[1][i]; Pa += sm[2][i]; }
        float photo = Pa / (Va + 1e-6f);
        float lr = La / (Va + 1e-6f);
        out[0] = photo + 0.2f * lr;   // W_PHOTO=1, W_LR=0.2
        out[1] = photo;
        out[2] = lr;
        out[3] = Va * (1.f / (float)(Bn * Hn * Wn));
    }
}

// ---- Fallback (fused strip kernel with atomics, only if ws too small) ------
namespace fb {
constexpr int RS = 8, SR = RS + 2, CW = 256, SC = CW + 2;
constexpr int NBX = (Wn + CW - 1) / CW, NSTRIP = Hn / RS;
constexpr int NBLK = NBX * NSTRIP * Bn;
}

__global__ __launch_bounds__(TPB) void stereo_fallback(
    const float* __restrict__ left, const float* __restrict__ right,
    const float* __restrict__ d_left, const float* __restrict__ d_right,
    const float* __restrict__ nonocc, float* __restrict__ acc,
    float* __restrict__ out)
{
    using namespace fb;
    __shared__ float sW[SR][SC];
    __shared__ float red[3][TPB / 64];
    const int t = threadIdx.x;
    const int bx = blockIdx.x, strip = blockIdx.y, b = blockIdx.z;
    const int y0 = strip * RS;
    const int x = bx * CW + t;
    const bool inb = (x < Wn);
    const int xc = min(x, Wn - 1);
    const float* leftB  = left   + (size_t)b * Cn * Hn * Wn;
    const float* rightB = right  + (size_t)b * Cn * Hn * Wn;
    const float* dL = d_left  + (size_t)b * Hn * Wn;
    const float* dR = d_right + (size_t)b * Hn * Wn;
    const float* no = nonocc  + (size_t)b * Hn * Wn;

    float vw_r[RS];
    float p_sum = 0.f, v_sum = 0.f, l_sum = 0.f;
    #pragma unroll
    for (int k = 0; k < RS; ++k) {
        int y = y0 + k;
        float d = dL[y * Wn + xc];
        float xs = (float)x - d;
        float vmask = (inb && xs >= 0.f && xs <= (float)(Wn - 1)) ? 1.f : 0.f;
        float vw = vmask * no[y * Wn + xc];
        vw_r[k] = vw; v_sum += vw;
        float drw = gath1(dR + (size_t)y * Wn, xs);
        float dd = d - drw;
        l_sum += sqrtf(dd * dd + kEps2) * vw;
    }
    const float xm_l = (x > 0) ? 1.f : 0.f;
    const float xm_r = (x < Wn - 1) ? 1.f : 0.f;
    const int xl = max(x - 1, 0), xr = min(x + 1, Wn - 1);
    const float inv_cx = (x == 0 || x == Wn - 1) ? 0.5f : (1.f / 3.f);
    const int g0 = bx * CW - 1;
    #pragma unroll
    for (int c = 0; c < Cn; ++c) {
        __syncthreads();
        const float* rchan = rightB + (size_t)c * Hn * Wn;
        #pragma unroll
        for (int r = 0; r < SR; ++r) {
            int y = y0 - 1 + r;
            bool yok = (y >= 0 && y < Hn);
            int g = g0 + t;
            float wv = 0.f;
            if (yok && g >= 0 && g < Wn)
                wv = gath1(rchan + (size_t)y * Wn, (float)g - dL[y * Wn + g]);
            sW[r][t] = wv;
            if (t < 2) {
                g = g0 + CW + t;
                wv = 0.f;
                if (yok && g >= 0 && g < Wn)
                    wv = gath1(rchan + (size_t)y * Wn, (float)g - dL[y * Wn + g]);
                sW[r][CW + t] = wv;
            }
        }
        __syncthreads();
        const float* lchan = leftB + (size_t)c * Hn * Wn;
        float lA[3][3], wA[3][3];
        #pragma unroll
        for (int r = 0; r < 2; ++r) {
            int y = y0 - 1 + r;
            int yy = min(max(y, 0), Hn - 1);
            float ym = (y >= 0 && y < Hn) ? 1.f : 0.f;
            const float* lrow = lchan + (size_t)yy * Wn;
            lA[r][0] = lrow[xl] * (ym * xm_l);
            lA[r][1] = lrow[xc] * ym;
            lA[r][2] = lrow[xr] * (ym * xm_r);
            wA[r][0] = sW[r][t]; wA[r][1] = sW[r][t + 1]; wA[r][2] = sW[r][t + 2];
        }
        #pragma unroll
        for (int k = 0; k < RS; ++k) {
            const int rn = k + 2, sn = rn % 3;
            int y = y0 - 1 + rn;
            int yy = min(max(y, 0), Hn - 1);
            float ym = (y >= 0 && y < Hn) ? 1.f : 0.f;
            const float* lrow = lchan + (size_t)yy * Wn;
            lA[sn][0] = lrow[xl] * (ym * xm_l);
            lA[sn][1] = lrow[xc] * ym;
            lA[sn][2] = lrow[xr] * (ym * xm_r);
            wA[sn][0] = sW[rn][t]; wA[sn][1] = sW[rn][t + 1]; wA[sn][2] = sW[rn][t + 2];
            float Sx = 0.f, Sy = 0.f, Sxx = 0.f, Syy = 0.f, Sxy = 0.f;
            #pragma unroll
            for (int s = 0; s < 3; ++s)
                #pragma unroll
                for (int j = 0; j < 3; ++j) {
                    float lv = lA[s][j], wv = wA[s][j];
                    Sx += lv; Sy += wv;
                    Sxx = fmaf(lv, lv, Sxx); Syy = fmaf(wv, wv, Syy); Sxy = fmaf(lv, wv, Sxy);
                }
            int yo = y0 + k;
            float inv = ((yo == 0 || yo == Hn - 1) ? 0.5f : (1.f / 3.f)) * inv_cx;
            float mu_x = Sx * inv, mu_y = Sy * inv;
            float sig_x = Sxx * inv - mu_x * mu_x;
            float sig_y = Syy * inv - mu_y * mu_y;
            float sig_xy = Sxy * inv - mu_x * mu_y;
            float num = (2.f * mu_x * mu_y + kC1) * (2.f * sig_xy + kC2);
            float den = (mu_x * mu_x + mu_y * mu_y + kC1) * (sig_x + sig_y + kC2);
            float ssim = num / (den + 1e-12f);
            float sm = fminf(fmaxf(0.5f * (1.f - ssim), 0.f), 1.f);
            int sc2 = (k + 1) % 3;
            float df = lA[sc2][1] - wA[sc2][1];
            p_sum += (A3 * sm + B3 * sqrtf(df * df + kEps2)) * vw_r[k];
        }
    }
    #pragma unroll
    for (int off = 32; off > 0; off >>= 1) {
        p_sum += __shfl_down(p_sum, off);
        v_sum += __shfl_down(v_sum, off);
        l_sum += __shfl_down(l_sum, off);
    }
    int lane = t & 63, wvi = t >> 6;
    if (lane == 0) { red[0][wvi] = p_sum; red[1][wvi] = v_sum; red[2][wvi] = l_sum; }
    __syncthreads();
    if (t == 0) {
        float P = 0.f, V = 0.f, L = 0.f;
        #pragma unroll
        for (int i = 0; i < TPB / 64; ++i) { P += red[0][i]; V += red[1][i]; L += red[2][i]; }
        atomicAdd(&acc[0], P);
        atomicAdd(&acc[1], V);
        atomicAdd(&acc[2], L);
        __threadfence();
        unsigned prev = atomicAdd((unsigned*)&acc[3], 1u);
        if (prev == fb::NBLK - 1) {
            float Pa = atomicAdd(&acc[0], 0.f);
            float Va = atomicAdd(&acc[1], 0.f);
            float La = atomicAdd(&acc[2], 0.f);
            float photo = Pa / (Va + 1e-6f);
            float lr = La / (Va + 1e-6f);
            out[0] = photo + 0.2f * lr;
            out[1] = photo;
            out[2] = lr;
            out[3] = Va * (1.f / (float)(Bn * Hn * Wn));
        }
    }
}

extern "C" void kernel_launch(void* const* d_in, const int* in_sizes, int n_in,
                              void* d_out, int out_size, void* d_ws, size_t ws_size,
                              hipStream_t stream) {
    const float* left   = (const float*)d_in[0];
    const float* right  = (const float*)d_in[1];
    const float* dl     = (const float*)d_in[2];
    const float* dr     = (const float*)d_in[3];
    const float* nonocc = (const float*)d_in[4];
    float* ws = (float*)d_ws;
    float* out = (float*)d_out;

    if (ws_size >= WS_NEED) {
        float* red1 = ws + RED_OFF;
        fused_main<<<NBLKF, TPB, 0, stream>>>(left, right, dl, dr, nonocc, red1);
        pass_reduce<<<1, 1024, 0, stream>>>(red1, out);
    } else {
        (void)hipMemsetAsync(ws, 0, 4 * sizeof(float), stream);
        dim3 grid(fb::NBX, fb::NSTRIP, Bn);
        stereo_fallback<<<grid, TPB, 0, stream>>>(left, right, dl, dr, nonocc, ws, out);
    }
}